// Round 2
// baseline (6815.453 us; speedup 1.0000x reference)
//
#include <hip/hip_runtime.h>

// Model: B=32, L1=512, L2=16, D=300, H=300, V=50000, C=3
#define B_  32
#define L1_ 512
#define L2_ 16
#define D_  300
#define H_  300

__device__ __forceinline__ float sigmoid_fast(float x) {
    return 1.0f / (1.0f + __expf(-x));
}
__device__ __forceinline__ float tanh_fast(float x) {
    x = fminf(fmaxf(x, -15.0f), 15.0f);
    float e = __expf(2.0f * x);
    return (e - 1.0f) / (e + 1.0f);
}
__device__ __forceinline__ float wred_sum(float v) {
    #pragma unroll
    for (int off = 32; off > 0; off >>= 1) v += __shfl_xor(v, off);
    return v;
}
__device__ __forceinline__ float wred_max(float v) {
    #pragma unroll
    for (int off = 32; off > 0; off >>= 1) v = fmaxf(v, __shfl_xor(v, off));
    return v;
}

// ---------------- gather rows of emb (row length 300 = 75 float4) ----------------
__global__ __launch_bounds__(256) void gather_kernel(const float* __restrict__ emb,
                                                     const int* __restrict__ ids,
                                                     float* __restrict__ out, int total) {
    for (int i = blockIdx.x * 256 + threadIdx.x; i < total; i += gridDim.x * 256) {
        int row = i / 75, c = i % 75;
        int id = ids[row];
        reinterpret_cast<float4*>(out)[i] =
            reinterpret_cast<const float4*>(emb + (size_t)id * 300)[c];
    }
}

// ---------------- fp32 GEMM: C[M,N] = A[M,K] @ W[N,K]^T (+ bias[n]) ----------------
#define TM 128
#define TN 64
#define TK 16
__global__ __launch_bounds__(256) void gemm_nt(const float* __restrict__ A,
                                               const float* __restrict__ W,
                                               const float* __restrict__ bias,
                                               float* __restrict__ C,
                                               int M, int N, int K) {
    __shared__ __align__(16) float As[TK][TM + 4];
    __shared__ __align__(16) float Bs[TK][TN + 4];
    const int tid = threadIdx.x;
    const int m0 = blockIdx.x * TM;
    const int n0 = blockIdx.y * TN;
    const int tx = tid & 15;
    const int ty = tid >> 4;
    const int lr = tid >> 2;
    const int lk = (tid & 3) << 2;

    float acc[8][4];
    #pragma unroll
    for (int i = 0; i < 8; ++i)
        #pragma unroll
        for (int j = 0; j < 4; ++j) acc[i][j] = 0.f;

    for (int k0 = 0; k0 < K; k0 += TK) {
        const bool kok = (k0 + lk + 3) < K;
        #pragma unroll
        for (int h = 0; h < 2; ++h) {
            float4 v = make_float4(0.f, 0.f, 0.f, 0.f);
            int m = m0 + lr + 64 * h;
            if (kok) v = *reinterpret_cast<const float4*>(&A[(size_t)m * K + k0 + lk]);
            As[lk + 0][lr + 64 * h] = v.x;
            As[lk + 1][lr + 64 * h] = v.y;
            As[lk + 2][lr + 64 * h] = v.z;
            As[lk + 3][lr + 64 * h] = v.w;
        }
        {
            float4 v = make_float4(0.f, 0.f, 0.f, 0.f);
            int n = n0 + lr;
            if (kok && n < N) v = *reinterpret_cast<const float4*>(&W[(size_t)n * K + k0 + lk]);
            Bs[lk + 0][lr] = v.x;
            Bs[lk + 1][lr] = v.y;
            Bs[lk + 2][lr] = v.z;
            Bs[lk + 3][lr] = v.w;
        }
        __syncthreads();
        #pragma unroll
        for (int k = 0; k < TK; ++k) {
            float4 a0 = *reinterpret_cast<const float4*>(&As[k][ty * 8]);
            float4 a1 = *reinterpret_cast<const float4*>(&As[k][ty * 8 + 4]);
            float4 bv = *reinterpret_cast<const float4*>(&Bs[k][tx * 4]);
            float av[8] = {a0.x, a0.y, a0.z, a0.w, a1.x, a1.y, a1.z, a1.w};
            float bb[4] = {bv.x, bv.y, bv.z, bv.w};
            #pragma unroll
            for (int i = 0; i < 8; ++i)
                #pragma unroll
                for (int j = 0; j < 4; ++j) acc[i][j] += av[i] * bb[j];
        }
        __syncthreads();
    }
    #pragma unroll
    for (int i = 0; i < 8; ++i) {
        int m = m0 + ty * 8 + i;
        #pragma unroll
        for (int j = 0; j < 4; ++j) {
            int n = n0 + tx * 4 + j;
            if (n < N) C[(size_t)m * N + n] = acc[i][j] + (bias ? bias[n] : 0.f);
        }
    }
}

// ---------------- attention: scores -> alpha -> context_ -> beta logits ----------------
__global__ __launch_bounds__(256) void attn_kernel(const float* __restrict__ c_proj,
                                                   const float* __restrict__ a_proj,
                                                   const float* __restrict__ asp_emb,
                                                   const float* __restrict__ lin,
                                                   const float* __restrict__ Vatt,
                                                   const float* __restrict__ Vw,
                                                   const float* __restrict__ bVw,
                                                   float* __restrict__ blogit) {
    const int b = blockIdx.y;
    const int chunk = blockIdx.x;
    __shared__ float sA[16 * 300];
    __shared__ float sE[16 * 300];
    __shared__ float sV[300];
    __shared__ float sW[300];
    const int tid = threadIdx.x;
    for (int i = tid; i < 16 * 300; i += 256) {
        sA[i] = a_proj[b * 4800 + i];
        sE[i] = asp_emb[b * 4800 + i];
    }
    for (int i = tid; i < 300; i += 256) {
        sV[i] = Vatt[i];
        sW[i] = Vw[i];
    }
    __syncthreads();
    const int wave = tid >> 6, lane = tid & 63;
    const float bvw = bVw[0];
    for (int li = 0; li < 4; ++li) {
        const int l = chunk * 16 + wave * 4 + li;
        const float* crow = c_proj + (size_t)(b * L1_ + l) * 300;
        float cr[5];
        #pragma unroll
        for (int i = 0; i < 5; ++i) {
            int d = lane + 64 * i;
            cr[i] = (d < 300) ? crow[d] : 0.f;
        }
        float sc[16];
        #pragma unroll
        for (int m = 0; m < 16; ++m) {
            float s = 0.f;
            #pragma unroll
            for (int i = 0; i < 5; ++i) {
                int d = lane + 64 * i;
                if (d < 300) s += tanh_fast(cr[i] + sA[m * 300 + d]) * sV[d];
            }
            s = wred_sum(s);
            sc[m] = s;
        }
        float mx = sc[0];
        #pragma unroll
        for (int m = 1; m < 16; ++m) mx = fmaxf(mx, sc[m]);
        float den = 0.f;
        #pragma unroll
        for (int m = 0; m < 16; ++m) {
            sc[m] = __expf(sc[m] - mx);
            den += sc[m];
        }
        const float inv = 1.f / den;
        const float* lrow = lin + (size_t)(b * L1_ + l) * 300;
        float acc = 0.f;
        #pragma unroll
        for (int i = 0; i < 5; ++i) {
            int d = lane + 64 * i;
            if (d < 300) {
                float cd = 0.f;
                #pragma unroll
                for (int m = 0; m < 16; ++m) cd += sc[m] * sE[m * 300 + d];
                acc += tanh_fast(lrow[d] + cd * inv) * sW[d];
            }
        }
        acc = wred_sum(acc);
        if (lane == 0) blogit[b * L1_ + l] = acc + bvw;
    }
}

// ---------------- beta softmax over L1=512 per batch ----------------
__global__ __launch_bounds__(256) void beta_softmax_kernel(const float* __restrict__ x,
                                                           float* __restrict__ y) {
    const int b = blockIdx.x, tid = threadIdx.x;
    __shared__ float red[4];
    const int wave = tid >> 6, lane = tid & 63;
    float v0 = x[b * 512 + tid];
    float v1 = x[b * 512 + 256 + tid];
    float m = wred_max(fmaxf(v0, v1));
    if (lane == 0) red[wave] = m;
    __syncthreads();
    m = fmaxf(fmaxf(red[0], red[1]), fmaxf(red[2], red[3]));
    float e0 = __expf(v0 - m), e1 = __expf(v1 - m);
    float s = wred_sum(e0 + e1);
    __syncthreads();
    if (lane == 0) red[wave] = s;
    __syncthreads();
    s = red[0] + red[1] + red[2] + red[3];
    const float inv = 1.f / s;
    y[b * 512 + tid] = e0 * inv;
    y[b * 512 + 256 + tid] = e1 * inv;
}

// ---------------- GRU v2: weights resident in registers ----------------
// grid (4, 32, 2): slice s owns hidden e in [75s, 75s+75); 225 threads own one
// full whh gate-row each (300 VGPRs). h exchanged via agent-scope atomics in
// global memory; 4-WG monotonic spin barrier per (b,dir) group.
__global__ __launch_bounds__(256, 1) void gru2_kernel(const float* __restrict__ xg_f,
                                                      const float* __restrict__ xg_b,
                                                      const float* __restrict__ whh_f,
                                                      const float* __restrict__ whh_b,
                                                      const float* __restrict__ bhh_f,
                                                      const float* __restrict__ bhh_b,
                                                      const float* __restrict__ beta,
                                                      float* __restrict__ hG,   // [64][300]
                                                      int* __restrict__ bar,    // [64]
                                                      float* __restrict__ senti) {
    const int s = blockIdx.x;    // 0..3
    const int b = blockIdx.y;    // 0..31
    const int rev = blockIdx.z;  // 0..1
    const int g = rev * 32 + b;
    const float* xg  = rev ? xg_b : xg_f;
    const float* whh = rev ? whh_b : whh_f;
    const float* bhh = rev ? bhh_b : bhh_f;
    float* hrow = hG + (size_t)g * 300;

    const int tid = threadIdx.x;
    const int e0 = s * 75;
    const bool act = tid < 225;
    const int gate = tid / 75;   // 0=r 1=z 2=n (valid when act)
    const int idx = tid % 75;

    __shared__ __align__(16) float hs[304];
    __shared__ float gg[3][80];

    // weight row -> registers (one-time, L2/LLC)
    float4 w4[75];
    float bh = 0.f;
    if (act) {
        const int row = gate * 300 + e0 + idx;
        bh = bhh[row];
        const float4* wp = reinterpret_cast<const float4*>(whh + (size_t)row * 300);
        #pragma unroll
        for (int j = 0; j < 75; ++j) w4[j] = wp[j];
    } else {
        #pragma unroll
        for (int j = 0; j < 75; ++j) w4[j] = make_float4(0.f, 0.f, 0.f, 0.f);
    }
    for (int i = tid; i < 304; i += 256) hs[i] = 0.f;
    float sacc = 0.f;
    int target = 0;
    __syncthreads();

    const float4* hs4 = reinterpret_cast<const float4*>(hs);
    for (int step = 0; step < 512; ++step) {
        const int t = rev ? (511 - step) : step;
        // issue xg/beta loads early (independent of h) so LLC latency hides
        // under the matvec
        float xr = 0.f, xz = 0.f, xn = 0.f, bt = 0.f;
        if (tid < 75) {
            const float* xrow = xg + (size_t)(b * 512 + t) * 900;
            const int e = e0 + tid;
            xr = xrow[e];
            xz = xrow[300 + e];
            xn = xrow[600 + e];
            bt = beta[b * 512 + t];
        }
        // matvec from registers: acc = bhh[row] + dot(whh[row,:], h)
        float acc = bh;
        #pragma unroll
        for (int j = 0; j < 75; ++j) {
            const float4 hv = hs4[j];
            acc = fmaf(w4[j].x, hv.x, acc);
            acc = fmaf(w4[j].y, hv.y, acc);
            acc = fmaf(w4[j].z, hv.z, acc);
            acc = fmaf(w4[j].w, hv.w, acc);
        }
        if (act) gg[gate][idx] = acc;
        __syncthreads();
        // gate update for this WG's h slice
        if (tid < 75) {
            const int e = e0 + tid;
            const float rr = sigmoid_fast(xr + gg[0][tid]);
            const float zz = sigmoid_fast(xz + gg[1][tid]);
            const float nn = tanh_fast(xn + rr * gg[2][tid]);
            const float hn = (1.f - zz) * nn + zz * hs[e];
            sacc = fmaf(bt, hn, sacc);
            __hip_atomic_store(&hrow[e], hn, __ATOMIC_RELAXED, __HIP_MEMORY_SCOPE_AGENT);
        }
        __syncthreads();  // drains vmcnt: h stores visible at coherence point
        target += 4;
        if (tid == 0) {
            __hip_atomic_fetch_add(&bar[g], 1, __ATOMIC_ACQ_REL, __HIP_MEMORY_SCOPE_AGENT);
            while (__hip_atomic_load(&bar[g], __ATOMIC_ACQUIRE, __HIP_MEMORY_SCOPE_AGENT) < target) {
                __builtin_amdgcn_s_sleep(1);
            }
        }
        __syncthreads();
        if (step < 511) {
            // gather fresh full h (agent-scope loads bypass stale caches)
            float v0 = __hip_atomic_load(&hrow[tid], __ATOMIC_RELAXED, __HIP_MEMORY_SCOPE_AGENT);
            float v1 = 0.f;
            if (tid < 44)
                v1 = __hip_atomic_load(&hrow[256 + tid], __ATOMIC_RELAXED, __HIP_MEMORY_SCOPE_AGENT);
            hs[tid] = v0;
            if (tid < 44) hs[256 + tid] = v1;
            __syncthreads();
        }
    }
    if (tid < 75) senti[b * 600 + rev * 300 + e0 + tid] = sacc;
}

// ---------------- final logits: (32,600) x (3,600)^T + outb ----------------
__global__ __launch_bounds__(64) void logits_kernel(const float* __restrict__ senti,
                                                    const float* __restrict__ outW,
                                                    const float* __restrict__ outb,
                                                    float* __restrict__ out) {
    const int b = blockIdx.x, lane = threadIdx.x;
    for (int c = 0; c < 3; ++c) {
        float s = 0.f;
        for (int hh = lane; hh < 600; hh += 64) s += senti[b * 600 + hh] * outW[c * 600 + hh];
        s = wred_sum(s);
        if (lane == 0) out[b * 3 + c] = s + outb[c];
    }
}

extern "C" void kernel_launch(void* const* d_in, const int* in_sizes, int n_in,
                              void* d_out, int out_size, void* d_ws, size_t ws_size,
                              hipStream_t stream) {
    const int* ctx_ids = (const int*)d_in[0];
    const int* asp_ids = (const int*)d_in[1];
    // d_in[2], d_in[3]: masks (all ones, unused by reference)
    const float* emb   = (const float*)d_in[4];
    const float* Wc    = (const float*)d_in[5];
    const float* Wa    = (const float*)d_in[6];
    const float* Vatt  = (const float*)d_in[7];
    const float* Wlin  = (const float*)d_in[8];
    const float* blin  = (const float*)d_in[9];
    const float* Vw    = (const float*)d_in[10];
    const float* bVw   = (const float*)d_in[11];
    const float* wih_f = (const float*)d_in[12];
    const float* whh_f = (const float*)d_in[13];
    const float* bih_f = (const float*)d_in[14];
    const float* bhh_f = (const float*)d_in[15];
    const float* wih_b = (const float*)d_in[16];
    const float* whh_b = (const float*)d_in[17];
    const float* bih_b = (const float*)d_in[18];
    const float* bhh_b = (const float*)d_in[19];
    const float* outW  = (const float*)d_in[20];
    const float* outb  = (const float*)d_in[21];
    float* ws = (float*)d_ws;

    size_t o = 0;
    float* ctx_emb = ws + o; o += (size_t)B_ * L1_ * D_;
    float* asp_emb = ws + o; o += (size_t)B_ * L2_ * D_;
    float* c_proj  = ws + o; o += (size_t)B_ * L1_ * D_;
    float* a_proj  = ws + o; o += (size_t)B_ * L2_ * D_;
    float* lin_buf = ws + o; o += (size_t)B_ * L1_ * D_;
    float* xg_f    = ws + o; o += (size_t)B_ * L1_ * 3 * H_;
    float* xg_b    = ws + o; o += (size_t)B_ * L1_ * 3 * H_;
    float* blogit  = ws + o; o += (size_t)B_ * L1_;
    float* beta    = ws + o; o += (size_t)B_ * L1_;
    float* senti   = ws + o; o += (size_t)B_ * 2 * H_;
    float* hG      = ws + o; o += (size_t)64 * 300;
    int*   bar     = (int*)(ws + o); o += 64;

    hipMemsetAsync(bar, 0, 64 * sizeof(int), stream);

    dim3 blk(256);
    const int tot_ctx = B_ * L1_ * 75;
    const int tot_asp = B_ * L2_ * 75;
    gather_kernel<<<dim3((tot_ctx + 255) / 256), blk, 0, stream>>>(emb, ctx_ids, ctx_emb, tot_ctx);
    gather_kernel<<<dim3((tot_asp + 255) / 256), blk, 0, stream>>>(emb, asp_ids, asp_emb, tot_asp);

    gemm_nt<<<dim3(16384 / 128, 5), blk, 0, stream>>>(ctx_emb, Wc, nullptr, c_proj, 16384, 300, 300);
    gemm_nt<<<dim3(16384 / 128, 5), blk, 0, stream>>>(ctx_emb, Wlin, blin, lin_buf, 16384, 300, 300);
    gemm_nt<<<dim3(512 / 128, 5), blk, 0, stream>>>(asp_emb, Wa, nullptr, a_proj, 512, 300, 300);
    gemm_nt<<<dim3(16384 / 128, 15), blk, 0, stream>>>(ctx_emb, wih_f, bih_f, xg_f, 16384, 900, 300);
    gemm_nt<<<dim3(16384 / 128, 15), blk, 0, stream>>>(ctx_emb, wih_b, bih_b, xg_b, 16384, 900, 300);

    attn_kernel<<<dim3(32, 32), blk, 0, stream>>>(c_proj, a_proj, asp_emb, lin_buf, Vatt, Vw, bVw, blogit);
    beta_softmax_kernel<<<dim3(32), blk, 0, stream>>>(blogit, beta);
    gru2_kernel<<<dim3(4, 32, 2), blk, 0, stream>>>(xg_f, xg_b, whh_f, whh_b, bhh_f, bhh_b,
                                                    beta, hG, bar, senti);
    logits_kernel<<<dim3(32), dim3(64), 0, stream>>>(senti, outW, outb, (float*)d_out);
}